// Round 8
// baseline (518.815 us; speedup 1.0000x reference)
//
#include <hip/hip_runtime.h>
#include <hip/hip_bf16.h>
#include <stdint.h>

// Problem constants (reference: T=10, N=2048, E=32768, H=256)
#define TT 10
#define NN 2048
#define EE 32768
#define HH 256

typedef short bf16x8 __attribute__((ext_vector_type(8)));
typedef float f32x4 __attribute__((ext_vector_type(4)));

__device__ __forceinline__ float b2f(unsigned short u) {
    unsigned int x = ((unsigned int)u) << 16;
    return __builtin_bit_cast(float, x);
}
__device__ __forceinline__ unsigned short f2b(float f) {
    unsigned int x = __builtin_bit_cast(unsigned int, f);
    unsigned int r = x + 0x7FFFu + ((x >> 16) & 1u);
    return (unsigned short)(r >> 16);
}

#define GLOAD_LDS16(g, l)                                                      \
    __builtin_amdgcn_global_load_lds(                                          \
        (const __attribute__((address_space(1))) void*)(g),                    \
        (__attribute__((address_space(3))) void*)(l), 16, 0, 0)

// ---------------- setup kernels ----------------

__global__ void cvt_bf16_kernel(const float* __restrict__ in,
                                unsigned short* __restrict__ out, int n) {
    int i = blockIdx.x * blockDim.x + threadIdx.x;
    int stride = gridDim.x * blockDim.x;
    for (; i < n; i += stride) out[i] = f2b(in[i]);
}

// W: [K][256] row-major -> Wt: [256][KPAD] bf16, zero-padded
__global__ void transpose_w_kernel(const float* __restrict__ W,
                                   unsigned short* __restrict__ Wt, int K, int KPAD) {
    int idx = blockIdx.x * blockDim.x + threadIdx.x;
    if (idx >= 256 * KPAD) return;
    int n = idx / KPAD, k = idx - n * KPAD;
    Wt[idx] = (k < K) ? f2b(W[k * 256 + n]) : (unsigned short)0;
}

__global__ void zero_f32_kernel(float* __restrict__ p, int n) {
    int i = blockIdx.x * blockDim.x + threadIdx.x;
    int stride = gridDim.x * blockDim.x;
    for (; i < n; i += stride) p[i] = 0.0f;
}

__global__ void count_kernel(const int* __restrict__ rows, int* __restrict__ counts) {
    int e = blockIdx.x * blockDim.x + threadIdx.x;
    if (e < EE) atomicAdd(&counts[rows[e]], 1);
}

// Exclusive scan of counts[0..2047] -> boff[0..2048]. One block, 256 threads.
__global__ __launch_bounds__(256) void scan_kernel(const int* __restrict__ counts,
                                                   int* __restrict__ boff) {
    __shared__ int part[256];
    int tid = threadIdx.x;
    int base = tid * 8;
    int local[8];
    int s = 0;
#pragma unroll
    for (int i = 0; i < 8; ++i) { local[i] = s; s += counts[base + i]; }
    part[tid] = s;
    __syncthreads();
    for (int offd = 1; offd < 256; offd <<= 1) {
        int v = (tid >= offd) ? part[tid - offd] : 0;
        __syncthreads();
        part[tid] += v;
        __syncthreads();
    }
    int pbase = (tid == 0) ? 0 : part[tid - 1];
#pragma unroll
    for (int i = 0; i < 8; ++i) boff[base + i] = pbase + local[i];
    if (tid == 255) boff[2048] = pbase + s;
}

// Scatter edges into row-sorted order: rs[pos]=row, cs[pos]=col.
__global__ void scatter_kernel(const int* __restrict__ rows, const int* __restrict__ cols,
                               const int* __restrict__ boff, int* __restrict__ cursor,
                               int* __restrict__ rs, int* __restrict__ cs) {
    int e = blockIdx.x * blockDim.x + threadIdx.x;
    if (e < EE) {
        int r = rows[e];
        int pos = boff[r] + atomicAdd(&cursor[r], 1);
        rs[pos] = r;
        cs[pos] = cols[e];
    }
}

// ---------------- edge megakernel (pipelined, 128 edges/block, 8 waves) ----------------
// Phases:
//  0) radial + cdiff -> LDS (CDs, Rs)
//  1) E1 = relu([h[rs]|h[cs]|radial] @ We1t^T + be1)  K=544, 17 BK=32 steps -> Es
//  2) E2 = relu(E1 @ We2t^T + be2)                    K=256, 8 steps -> Es
//  3) m  = relu(E2 @ Wc1t^T + bc1) . Wc2              K=256, 8 steps -> Ms
//  epilogue: node-boundary-flush agg (Es) and csum (CDs*m) atomics.
// K-loops are software-pipelined: stage(step s+1) issued before mfma(step s),
// one __syncthreads per step (drains prior stage; flight hidden under MFMA).
// A/B LDS swizzle: 16B slot ^= row&3 (bank-uniform), applied on global source.
// Es swizzle: elem col ^= (row&7)<<3.
__global__ __launch_bounds__(512, 1) void edge_mega_kernel(
    const float* __restrict__ x, const unsigned short* __restrict__ hb,
    const unsigned short* __restrict__ We1t, const float* __restrict__ be1,
    const unsigned short* __restrict__ We2t, const float* __restrict__ be2,
    const unsigned short* __restrict__ Wc1t, const float* __restrict__ bc1,
    const float* __restrict__ Wc2,
    const int* __restrict__ rs, const int* __restrict__ cs,
    float* __restrict__ aggf, float* __restrict__ csum) {
    __shared__ unsigned short As[2 * 128 * 32];   // 16 KB dbuf
    __shared__ unsigned short Bs[2 * 256 * 32];   // 32 KB dbuf
    __shared__ unsigned short Es[128 * 256];      // 64 KB
    __shared__ float CDs[128][12];                // 6 KB
    __shared__ unsigned short Rs[128][16];        // 4 KB
    __shared__ float Ms[128][4];                  // 2 KB

    int tid = threadIdx.x;
    int lane = tid & 63, w = tid >> 6;
    int wr = w >> 2, wc = w & 3;
    int lr = lane & 15, lq = lane >> 4;
    int blockRow = blockIdx.x * 128;
    int tt = blockRow >> 15;                  // uniform timestep per block
    int sb = blockRow & (EE - 1);             // base sorted-index

    // ---- phase 0: radial + cdiff for 128 sorted edges ----
    if (tid < 128) {
        int s = sb + tid;
        int r = rs[s], c = cs[s];
        const float* xr = x + ((size_t)tt * NN + r) * 12;
        const float* xc = x + ((size_t)tt * NN + c) * 12;
        float cd[12];
#pragma unroll
        for (int i = 0; i < 12; ++i) {
            cd[i] = xr[i] - xc[i];
            CDs[tid][i] = cd[i];
        }
        float g[16], ss = 0.f;
#pragma unroll
        for (int j = 0; j < 4; ++j)
#pragma unroll
            for (int k = 0; k < 4; ++k) {
                float v = cd[j * 3] * cd[k * 3] + cd[j * 3 + 1] * cd[k * 3 + 1] +
                          cd[j * 3 + 2] * cd[k * 3 + 2];
                g[j * 4 + k] = v;
                ss += v * v;
            }
        float inv = 1.f / fmaxf(sqrtf(ss), 1e-12f);
#pragma unroll
        for (int i = 0; i < 16; ++i) Rs[tid][i] = f2b(g[i] * inv);
    }

    // ---- staging geometry ----
    int srow = tid >> 2, sslot = tid & 3;
    int xoff = ((sslot ^ (srow & 3)) * 8);    // pre-swizzled source offset (elems)
    const unsigned short *hrp, *hcp;
    {
        int ir = rs[sb + srow], ic = cs[sb + srow];
        hrp = hb + ((size_t)tt * NN + ir) * 256 + xoff;
        hcp = hb + ((size_t)tt * NN + ic) * 256 + xoff - 256;
    }
    int axoff = (lq ^ (lr & 3)) * 8;          // mfma A/B read swizzle (elems)

    f32x4 acc[4][4];
#pragma unroll
    for (int m = 0; m < 4; ++m)
#pragma unroll
        for (int n = 0; n < 4; ++n) acc[m][n] = (f32x4){0.f, 0.f, 0.f, 0.f};

    auto stageB = [&](const unsigned short* Wt, int KPAD, int buf, int k0) {
        GLOAD_LDS16(Wt + (size_t)srow * KPAD + k0 + xoff, Bs + buf * 8192 + w * 512);
        GLOAD_LDS16(Wt + (size_t)(128 + srow) * KPAD + k0 + xoff,
                    Bs + buf * 8192 + 4096 + w * 512);
    };
    auto mfma32 = [&](int buf) {
        const unsigned short* Ab = As + buf * 4096;
        const unsigned short* Bb = Bs + buf * 8192;
        bf16x8 a[4], b[4];
#pragma unroll
        for (int m = 0; m < 4; ++m)
            a[m] = *reinterpret_cast<const bf16x8*>(
                Ab + (wr * 64 + m * 16 + lr) * 32 + axoff);
#pragma unroll
        for (int n = 0; n < 4; ++n)
            b[n] = *reinterpret_cast<const bf16x8*>(
                Bb + (wc * 64 + n * 16 + lr) * 32 + axoff);
#pragma unroll
        for (int m = 0; m < 4; ++m)
#pragma unroll
            for (int n = 0; n < 4; ++n)
                acc[m][n] = __builtin_amdgcn_mfma_f32_16x16x32_bf16(
                    a[m], b[n], acc[m][n], 0, 0, 0);
    };
    auto mfma_es = [&](int buf, int k0) {
        const unsigned short* Bb = Bs + buf * 8192;
        int ex = (k0 + lq * 8) ^ ((lr & 7) << 3);
        bf16x8 a[4], b[4];
#pragma unroll
        for (int m = 0; m < 4; ++m)
            a[m] = *reinterpret_cast<const bf16x8*>(
                Es + (wr * 64 + m * 16 + lr) * 256 + ex);
#pragma unroll
        for (int n = 0; n < 4; ++n)
            b[n] = *reinterpret_cast<const bf16x8*>(
                Bb + (wc * 64 + n * 16 + lr) * 32 + axoff);
#pragma unroll
        for (int m = 0; m < 4; ++m)
#pragma unroll
            for (int n = 0; n < 4; ++n)
                acc[m][n] = __builtin_amdgcn_mfma_f32_16x16x32_bf16(
                    a[m], b[n], acc[m][n], 0, 0, 0);
    };
    auto epi_es = [&](const float* __restrict__ bias) {
        float bv[4];
#pragma unroll
        for (int n = 0; n < 4; ++n) bv[n] = bias[wc * 64 + n * 16 + lr];
#pragma unroll
        for (int m = 0; m < 4; ++m)
#pragma unroll
            for (int rr = 0; rr < 4; ++rr) {
                int row = wr * 64 + m * 16 + lq * 4 + rr;
                int xsw = (row & 7) << 3;
#pragma unroll
                for (int n = 0; n < 4; ++n) {
                    int col = wc * 64 + n * 16 + lr;
                    float v = fmaxf(acc[m][n][rr] + bv[n], 0.f);
                    Es[row * 256 + (col ^ xsw)] = f2b(v);
                }
            }
    };
    auto acc_reset = [&]() {
#pragma unroll
        for (int m = 0; m < 4; ++m)
#pragma unroll
            for (int n = 0; n < 4; ++n) acc[m][n] = (f32x4){0.f, 0.f, 0.f, 0.f};
    };

    // ---- GEMM1: K=544 (h[rs] 0..255 | h[cs] 256..511 | radial 512..543) ----
    {
        // prologue stage (buf 0, step 0)
        GLOAD_LDS16(hrp, As + w * 512);
        stageB(We1t, 544, 0, 0);
        int cur = 0;
        for (int s = 0; s < 17; ++s) {
            __syncthreads();   // drains stage(s) [and step s-1 reads]
            int nxt = cur ^ 1;
            if (s < 15) {
                const unsigned short* sa =
                    (s + 1 < 8) ? hrp + 32 * (s + 1) : hcp + 32 * (s + 1);
                GLOAD_LDS16(sa, As + nxt * 4096 + w * 512);
                stageB(We1t, 544, nxt, 32 * (s + 1));
            } else if (s == 15) {
                // radial tail (step 16): fill As[nxt] from Rs via ds_write
                int ls = sslot ^ (srow & 3);
                bf16x8 v = {};
                if (ls < 2) {
#pragma unroll
                    for (int ii = 0; ii < 8; ++ii)
                        v[ii] = (short)Rs[srow][ls * 8 + ii];
                }
                *reinterpret_cast<bf16x8*>(As + nxt * 4096 + tid * 8) = v;
                stageB(We1t, 544, nxt, 512);
            }
            mfma32(cur);
            cur ^= 1;
        }
    }
    __syncthreads();               // last-step reads done; buffers free
    stageB(We2t, 256, 0, 0);       // prefetch GEMM2 step 0 (flies during epi1)
    epi_es(be1);                   // E1 -> Es

    // ---- GEMM2: E2 = relu(E1 @ We2t^T + be2), K=256 ----
    acc_reset();
    {
        int cur = 0;
        for (int s = 0; s < 8; ++s) {
            __syncthreads();
            if (s < 7) stageB(We2t, 256, cur ^ 1, 32 * (s + 1));
            mfma_es(cur, 32 * s);
            cur ^= 1;
        }
    }
    __syncthreads();               // all Es(E1) + Bs reads done
    stageB(Wc1t, 256, 0, 0);       // prefetch GEMM3 step 0 (flies during epi2)
    epi_es(be2);                   // E2 -> Es (overwrite)

    // ---- GEMM3: m = relu(E2 @ Wc1t^T + bc1) . Wc2, K=256 ----
    acc_reset();
    {
        int cur = 0;
        for (int s = 0; s < 8; ++s) {
            __syncthreads();
            if (s < 7) stageB(Wc1t, 256, cur ^ 1, 32 * (s + 1));
            mfma_es(cur, 32 * s);
            cur ^= 1;
        }
    }
    {   // epilogue 3: per-row dot with Wc2, 16-lane reduce, partials to Ms
        float bv[4], wv[4];
#pragma unroll
        for (int n = 0; n < 4; ++n) {
            int col = wc * 64 + n * 16 + lr;
            bv[n] = bc1[col];
            wv[n] = Wc2[col];
        }
#pragma unroll
        for (int m = 0; m < 4; ++m)
#pragma unroll
            for (int rr = 0; rr < 4; ++rr) {
                float p = 0.f;
#pragma unroll
                for (int n = 0; n < 4; ++n)
                    p += fmaxf(acc[m][n][rr] + bv[n], 0.f) * wv[n];
                p += __shfl_xor(p, 1);
                p += __shfl_xor(p, 2);
                p += __shfl_xor(p, 4);
                p += __shfl_xor(p, 8);
                if (lr == 0) Ms[wr * 64 + m * 16 + lq * 4 + rr][wc] = p;
            }
    }
    __syncthreads();
    if (tid < 128) Ms[tid][0] += Ms[tid][1] + Ms[tid][2] + Ms[tid][3];
    __syncthreads();

    // ---- agg: sorted rows -> boundary-flush atomics. 2 threads/col (row halves) ----
    {
        int colw = tid & 255;
        int i0 = (tid >> 8) * 64;
        float accv = 0.f;
        for (int i = i0; i < i0 + 64; ++i) {
            int ncur = rs[sb + i];
            accv += b2f(Es[i * 256 + (colw ^ ((i & 7) << 3))]);
            if (i == i0 + 63 || rs[sb + i + 1] != ncur) {
                atomicAdd(&aggf[((size_t)tt * NN + ncur) * 256 + colw], accv);
                accv = 0.f;
            }
        }
    }
    // ---- csum: same boundary-flush over CDs * m ----
    if (tid < 24) {
        int g = tid / 12, c = tid - g * 12;
        int i0 = g * 64;
        float a = 0.f;
        for (int i = i0; i < i0 + 64; ++i) {
            int ncur = rs[sb + i];
            a += CDs[i][c] * Ms[i][0];
            if (i == i0 + 63 || rs[sb + i + 1] != ncur) {
                atomicAdd(&csum[((size_t)tt * NN + ncur) * 12 + c], a);
                a = 0.f;
            }
        }
    }
}

// ---------------- node GEMM (m97 128x128, BK=32) ----------------
// EPI 0: relu -> bf16 store.  EPI 2: f32 store outf = acc + bias + resid.
template<int EPI>
__global__ __launch_bounds__(256) void gemm_kernel(
    const unsigned short* __restrict__ A, const unsigned short* __restrict__ Wt,
    const float* __restrict__ bias, unsigned short* __restrict__ Cb, int KPAD,
    const float* __restrict__ resid, float* __restrict__ outf) {
    __shared__ unsigned short As[128 * 32];
    __shared__ unsigned short Bs[128 * 32];
    int tid = threadIdx.x;
    int lane = tid & 63, w = tid >> 6;
    int wr = w >> 1, wc = w & 1;
    int blockRow = blockIdx.x * 128, colBase = blockIdx.y * 128;
    int l4 = lane >> 2;
    int seg = lane & 3;

    int ar0 = blockRow + w * 16 + l4;
    int br0 = colBase + w * 16 + l4;
    const unsigned short* pA0 = A + (size_t)ar0 * KPAD + seg * 8;
    const unsigned short* pA1 = pA0 + (size_t)64 * KPAD;
    const unsigned short* pB0 = Wt + (size_t)br0 * KPAD + seg * 8;
    const unsigned short* pB1 = pB0 + (size_t)64 * KPAD;

    unsigned short* ldsA = As + w * 512;
    unsigned short* ldsB = Bs + w * 512;

    f32x4 acc[4][4] = {};
    int lr = lane & 15, lq = lane >> 4;

    for (int k0 = 0; k0 < KPAD; k0 += 32) {
        GLOAD_LDS16(pA0 + k0, ldsA);
        GLOAD_LDS16(pA1 + k0, ldsA + 2048);
        GLOAD_LDS16(pB0 + k0, ldsB);
        GLOAD_LDS16(pB1 + k0, ldsB + 2048);
        __syncthreads();
        bf16x8 a[4], b[4];
#pragma unroll
        for (int m = 0; m < 4; ++m)
            a[m] = *reinterpret_cast<const bf16x8*>(
                As + (wr * 64 + m * 16 + lr) * 32 + lq * 8);
#pragma unroll
        for (int n = 0; n < 4; ++n)
            b[n] = *reinterpret_cast<const bf16x8*>(
                Bs + (wc * 64 + n * 16 + lr) * 32 + lq * 8);
#pragma unroll
        for (int m = 0; m < 4; ++m)
#pragma unroll
            for (int n = 0; n < 4; ++n)
                acc[m][n] = __builtin_amdgcn_mfma_f32_16x16x32_bf16(
                    a[m], b[n], acc[m][n], 0, 0, 0);
        __syncthreads();
    }

    float bv[4];
#pragma unroll
    for (int n = 0; n < 4; ++n) bv[n] = bias[colBase + wc * 64 + n * 16 + lr];

#pragma unroll
    for (int m = 0; m < 4; ++m)
#pragma unroll
        for (int r = 0; r < 4; ++r) {
            int row = blockRow + wr * 64 + m * 16 + lq * 4 + r;
#pragma unroll
            for (int n = 0; n < 4; ++n) {
                int col = colBase + wc * 64 + n * 16 + lr;
                float v = acc[m][n][r] + bv[n];
                if (EPI == 2) {
                    outf[(size_t)row * 256 + col] =
                        v + resid[(size_t)row * 256 + col];
                } else {
                    Cb[(size_t)row * 256 + col] = f2b(fmaxf(v, 0.f));
                }
            }
        }
}

// node_in[nf][768] = [others(256 f32), h(256 bf16), agg(256 f32)] as bf16
__global__ void nodein_kernel(const float* __restrict__ others,
                              const unsigned short* __restrict__ hb,
                              const float* __restrict__ aggf,
                              unsigned short* __restrict__ node_in) {
    int idx = blockIdx.x * blockDim.x + threadIdx.x;
    int stride = gridDim.x * blockDim.x;
    const int total = TT * NN * 192;
    for (; idx < total; idx += stride) {
        int nf = idx / 192, c4 = (idx - nf * 192) * 4;
        ushort4 v;
        if (c4 < 256) {
            float4 o = *reinterpret_cast<const float4*>(others + (size_t)nf * 256 + c4);
            v.x = f2b(o.x); v.y = f2b(o.y); v.z = f2b(o.z); v.w = f2b(o.w);
        } else if (c4 < 512) {
            v = *reinterpret_cast<const ushort4*>(hb + (size_t)nf * 256 + (c4 - 256));
        } else {
            float4 a = *reinterpret_cast<const float4*>(aggf + (size_t)nf * 256 + (c4 - 512));
            v.x = f2b(a.x); v.y = f2b(a.y); v.z = f2b(a.z); v.w = f2b(a.w);
        }
        *reinterpret_cast<ushort4*>(node_in + (size_t)nf * 768 + c4) = v;
    }
}

__global__ void coordout_kernel(const float* __restrict__ x, const int* __restrict__ counts,
                                const float* __restrict__ csum, float* __restrict__ outc) {
    int idx = blockIdx.x * blockDim.x + threadIdx.x;
    if (idx >= TT * NN * 12) return;
    int n = (idx / 12) & (NN - 1);
    float cnt = (float)(counts[n] > 0 ? counts[n] : 1);
    outc[idx] = x[idx] + csum[idx] / cnt;
}

// ---------------- launch ----------------

extern "C" void kernel_launch(void* const* d_in, const int* in_sizes, int n_in,
                              void* d_out, int out_size, void* d_ws, size_t ws_size,
                              hipStream_t stream) {
    const float* x = (const float*)d_in[0];
    const float* h = (const float*)d_in[1];
    const float* others = (const float*)d_in[2];
    const float* We1 = (const float*)d_in[3];
    const float* be1 = (const float*)d_in[4];
    const float* We2 = (const float*)d_in[5];
    const float* be2 = (const float*)d_in[6];
    const float* Wn1 = (const float*)d_in[7];
    const float* bn1 = (const float*)d_in[8];
    const float* Wn2 = (const float*)d_in[9];
    const float* bn2 = (const float*)d_in[10];
    const float* Wc1 = (const float*)d_in[11];
    const float* bc1 = (const float*)d_in[12];
    const float* Wc2 = (const float*)d_in[13];
    const int* ei = (const int*)d_in[14];
    const int* rows = ei;
    const int* cols = ei + EE;

    char* wsb = (char*)d_ws;
    size_t off = 0;
    auto alloc = [&](size_t bytes) {
        void* p = wsb + off;
        off = (off + bytes + 255) & ~(size_t)255;
        return p;
    };
    const int TNH = TT * NN * HH;
    unsigned short* hb = (unsigned short*)alloc((size_t)TNH * 2);
    unsigned short* We1t = (unsigned short*)alloc(256 * 544 * 2);
    unsigned short* We2t = (unsigned short*)alloc(256 * 256 * 2);
    unsigned short* Wn1t = (unsigned short*)alloc(256 * 768 * 2);
    unsigned short* Wn2t = (unsigned short*)alloc(256 * 256 * 2);
    unsigned short* Wc1t = (unsigned short*)alloc(256 * 256 * 2);
    float* aggf = (float*)alloc((size_t)TT * NN * 256 * 4);  // contiguous zero region:
    float* csum = (float*)alloc((size_t)TT * NN * 12 * 4);   // aggf | csum
    int* counts = (int*)alloc((size_t)2048 * 4);   // counts | cursor (zeroed together)
    int* cursor = (int*)alloc((size_t)2048 * 4);
    int* boff = (int*)alloc((size_t)2049 * 4);
    int* rs = (int*)alloc((size_t)EE * 4);
    int* cs = (int*)alloc((size_t)EE * 4);
    unsigned short* node_in = (unsigned short*)alloc((size_t)TT * NN * 768 * 2);
    unsigned short* Z = (unsigned short*)alloc((size_t)TT * NN * 256 * 2);
    (void)ws_size;

    // ---- setup ----
    cvt_bf16_kernel<<<2048, 256, 0, stream>>>(h, hb, TNH);
    transpose_w_kernel<<<544, 256, 0, stream>>>(We1, We1t, 528, 544);
    transpose_w_kernel<<<256, 256, 0, stream>>>(We2, We2t, 256, 256);
    transpose_w_kernel<<<768, 256, 0, stream>>>(Wn1, Wn1t, 768, 768);
    transpose_w_kernel<<<256, 256, 0, stream>>>(Wn2, Wn2t, 256, 256);
    transpose_w_kernel<<<256, 256, 0, stream>>>(Wc1, Wc1t, 256, 256);
    zero_f32_kernel<<<16, 256, 0, stream>>>((float*)counts, 4096);  // counts+cursor
    count_kernel<<<EE / 256, 256, 0, stream>>>(rows, counts);
    scan_kernel<<<1, 256, 0, stream>>>(counts, boff);
    scatter_kernel<<<EE / 256, 256, 0, stream>>>(rows, cols, boff, cursor, rs, cs);
    zero_f32_kernel<<<2048, 256, 0, stream>>>(aggf, TT * NN * 256 + TT * NN * 12);

    float* houtf = (float*)d_out;
    float* coutf = (float*)d_out + (size_t)TT * NN * HH;

    // ---- fused edge pipeline: all T, sorted edges, pipelined K-loops ----
    edge_mega_kernel<<<TT * EE / 128, 512, 0, stream>>>(
        x, hb, We1t, be1, We2t, be2, Wc1t, bc1, Wc2, rs, cs, aggf, csum);

    // ---- node pipeline ----
    nodein_kernel<<<2048, 256, 0, stream>>>(others, hb, aggf, node_in);
    gemm_kernel<0><<<dim3(TT * NN / 128, 2), 256, 0, stream>>>(
        node_in, Wn1t, bn1, Z, 768, nullptr, nullptr);
    gemm_kernel<2><<<dim3(TT * NN / 128, 2), 256, 0, stream>>>(
        Z, Wn2t, bn2, nullptr, 256, h, houtf);

    coordout_kernel<<<(TT * NN * 12 + 255) / 256, 256, 0, stream>>>(
        x, counts, csum, coutf);
}

// Round 9
// 436.412 us; speedup vs baseline: 1.1888x; 1.1888x over previous
//
#include <hip/hip_runtime.h>
#include <hip/hip_bf16.h>
#include <stdint.h>

// Problem constants (reference: T=10, N=2048, E=32768, H=256)
#define TT 10
#define NN 2048
#define EE 32768
#define HH 256

typedef short bf16x8 __attribute__((ext_vector_type(8)));
typedef float f32x4 __attribute__((ext_vector_type(4)));

__device__ __forceinline__ float b2f(unsigned short u) {
    unsigned int x = ((unsigned int)u) << 16;
    return __builtin_bit_cast(float, x);
}
__device__ __forceinline__ unsigned short f2b(float f) {
    unsigned int x = __builtin_bit_cast(unsigned int, f);
    unsigned int r = x + 0x7FFFu + ((x >> 16) & 1u);
    return (unsigned short)(r >> 16);
}

#define GLOAD_LDS16(g, l)                                                      \
    __builtin_amdgcn_global_load_lds(                                          \
        (const __attribute__((address_space(1))) void*)(g),                    \
        (__attribute__((address_space(3))) void*)(l), 16, 0, 0)

// ---------------- setup kernels ----------------

__global__ void cvt_bf16_kernel(const float* __restrict__ in,
                                unsigned short* __restrict__ out, int n) {
    int i = blockIdx.x * blockDim.x + threadIdx.x;
    int stride = gridDim.x * blockDim.x;
    for (; i < n; i += stride) out[i] = f2b(in[i]);
}

// W: [K][256] row-major -> Wt: [256][KPAD] bf16, zero-padded
__global__ void transpose_w_kernel(const float* __restrict__ W,
                                   unsigned short* __restrict__ Wt, int K, int KPAD) {
    int idx = blockIdx.x * blockDim.x + threadIdx.x;
    if (idx >= 256 * KPAD) return;
    int n = idx / KPAD, k = idx - n * KPAD;
    Wt[idx] = (k < K) ? f2b(W[k * 256 + n]) : (unsigned short)0;
}

__global__ void zero_f32_kernel(float* __restrict__ p, int n) {
    int i = blockIdx.x * blockDim.x + threadIdx.x;
    int stride = gridDim.x * blockDim.x;
    for (; i < n; i += stride) p[i] = 0.0f;
}

__global__ void count_kernel(const int* __restrict__ rows, int* __restrict__ counts) {
    int e = blockIdx.x * blockDim.x + threadIdx.x;
    if (e < EE) atomicAdd(&counts[rows[e]], 1);
}

// Exclusive scan of counts[0..2047] -> boff[0..2048]. One block, 256 threads.
__global__ __launch_bounds__(256) void scan_kernel(const int* __restrict__ counts,
                                                   int* __restrict__ boff) {
    __shared__ int part[256];
    int tid = threadIdx.x;
    int base = tid * 8;
    int local[8];
    int s = 0;
#pragma unroll
    for (int i = 0; i < 8; ++i) { local[i] = s; s += counts[base + i]; }
    part[tid] = s;
    __syncthreads();
    for (int offd = 1; offd < 256; offd <<= 1) {
        int v = (tid >= offd) ? part[tid - offd] : 0;
        __syncthreads();
        part[tid] += v;
        __syncthreads();
    }
    int pbase = (tid == 0) ? 0 : part[tid - 1];
#pragma unroll
    for (int i = 0; i < 8; ++i) boff[base + i] = pbase + local[i];
    if (tid == 255) boff[2048] = pbase + s;
}

// Scatter edges into row-sorted order: rs[pos]=row, cs[pos]=col.
__global__ void scatter_kernel(const int* __restrict__ rows, const int* __restrict__ cols,
                               const int* __restrict__ boff, int* __restrict__ cursor,
                               int* __restrict__ rs, int* __restrict__ cs) {
    int e = blockIdx.x * blockDim.x + threadIdx.x;
    if (e < EE) {
        int r = rows[e];
        int pos = boff[r] + atomicAdd(&cursor[r], 1);
        rs[pos] = r;
        cs[pos] = cols[e];
    }
}

// ---------------- edge megakernel ----------------
// Round-7 geometry (64 sorted edges/block, 256 thr, 4 waves, 2 blocks/CU)
// with a BK=32 double-buffered pipeline: stage(s+1) issued after the barrier,
// before mfma(s) — stage flight hidden under the MFMA phase.
// A/B LDS rows are 32 elems (64 B): swizzle 16B-slot ^= (row>>1)&3
// (2-way max = free). Es rows 256 elems: proven swizzle col ^= (row&7)<<3.
// Swizzles applied on the GLOBAL SOURCE address; LDS written linearly.
__global__ __launch_bounds__(256, 2) void edge_mega_kernel(
    const float* __restrict__ x, const unsigned short* __restrict__ hb,
    const unsigned short* __restrict__ We1t, const float* __restrict__ be1,
    const unsigned short* __restrict__ We2t, const float* __restrict__ be2,
    const unsigned short* __restrict__ Wc1t, const float* __restrict__ bc1,
    const float* __restrict__ Wc2,
    const int* __restrict__ rs, const int* __restrict__ cs,
    float* __restrict__ aggf, float* __restrict__ csum) {
    __shared__ unsigned short As[2][64 * 32];    // 2 x 4 KB
    __shared__ unsigned short Bs[2][256 * 32];   // 2 x 16 KB
    __shared__ unsigned short Es[64 * 256];      // 32 KB (swizzled)
    __shared__ float CDs[64][12];                // 3 KB
    __shared__ unsigned short Rs[64][16];        // 2 KB
    __shared__ float Ms[64][4];                  // 1 KB

    int tid = threadIdx.x;
    int lane = tid & 63, w = tid >> 6;
    int lr = lane & 15, lq = lane >> 4;
    int blockRow = blockIdx.x * 64;
    int tt = blockRow >> 15;                  // uniform timestep per block
    int sb = blockRow & (EE - 1);             // base sorted-index

    // ---- phase 0: radial + cdiff for this block's 64 sorted edges ----
    if (tid < 64) {
        int s = sb + tid;
        int r = rs[s], c = cs[s];
        const float* xr = x + ((size_t)tt * NN + r) * 12;
        const float* xc = x + ((size_t)tt * NN + c) * 12;
        float cd[12];
#pragma unroll
        for (int i = 0; i < 12; ++i) {
            cd[i] = xr[i] - xc[i];
            CDs[tid][i] = cd[i];
        }
        float g[16], ss = 0.f;
#pragma unroll
        for (int j = 0; j < 4; ++j)
#pragma unroll
            for (int k = 0; k < 4; ++k) {
                float v = cd[j * 3] * cd[k * 3] + cd[j * 3 + 1] * cd[k * 3 + 1] +
                          cd[j * 3 + 2] * cd[k * 3 + 2];
                g[j * 4 + k] = v;
                ss += v * v;
            }
        float inv = 1.f / fmaxf(sqrtf(ss), 1e-12f);
#pragma unroll
        for (int i = 0; i < 16; ++i) Rs[tid][i] = f2b(g[i] * inv);
    }

    // ---- staging geometry: thread -> (row tid>>2, 16B slot tid&3) ----
    int srow = tid >> 2, sslot = tid & 3;
    int xoff = (sslot ^ ((srow >> 1) & 3)) * 8;   // pre-swizzled source offset
    const unsigned short* hrp =
        hb + ((size_t)tt * NN + rs[sb + srow]) * 256 + xoff;
    const unsigned short* hcp =
        hb + ((size_t)tt * NN + cs[sb + srow]) * 256 + xoff - 256;
    int axoff = (lq ^ ((lr >> 1) & 3)) * 8;       // mfma A/B read swizzle

    f32x4 acc[4][4];
#pragma unroll
    for (int m = 0; m < 4; ++m)
#pragma unroll
        for (int n = 0; n < 4; ++n) acc[m][n] = (f32x4){0.f, 0.f, 0.f, 0.f};

    auto stageB = [&](const unsigned short* Wt, int KPAD, int buf, int k0) {
#pragma unroll
        for (int i = 0; i < 4; ++i)
            GLOAD_LDS16(Wt + (size_t)(i * 64 + srow) * KPAD + k0 + xoff,
                        Bs[buf] + i * 2048 + w * 512);
    };
    auto mfma32 = [&](int buf) {
        bf16x8 a[4], b[4];
#pragma unroll
        for (int m = 0; m < 4; ++m)
            a[m] = *reinterpret_cast<const bf16x8*>(
                As[buf] + (m * 16 + lr) * 32 + axoff);
#pragma unroll
        for (int n = 0; n < 4; ++n)
            b[n] = *reinterpret_cast<const bf16x8*>(
                Bs[buf] + (w * 64 + n * 16 + lr) * 32 + axoff);
#pragma unroll
        for (int m = 0; m < 4; ++m)
#pragma unroll
            for (int n = 0; n < 4; ++n)
                acc[m][n] = __builtin_amdgcn_mfma_f32_16x16x32_bf16(
                    a[m], b[n], acc[m][n], 0, 0, 0);
    };
    auto mfma_es = [&](int buf, int k0) {
        int ex = (k0 + lq * 8) ^ ((lr & 7) << 3);
        bf16x8 a[4], b[4];
#pragma unroll
        for (int m = 0; m < 4; ++m)
            a[m] = *reinterpret_cast<const bf16x8*>(
                Es + (m * 16 + lr) * 256 + ex);
#pragma unroll
        for (int n = 0; n < 4; ++n)
            b[n] = *reinterpret_cast<const bf16x8*>(
                Bs[buf] + (w * 64 + n * 16 + lr) * 32 + axoff);
#pragma unroll
        for (int m = 0; m < 4; ++m)
#pragma unroll
            for (int n = 0; n < 4; ++n)
                acc[m][n] = __builtin_amdgcn_mfma_f32_16x16x32_bf16(
                    a[m], b[n], acc[m][n], 0, 0, 0);
    };
    auto epi_es = [&](const float* __restrict__ bias) {
        float bv[4];
#pragma unroll
        for (int n = 0; n < 4; ++n) bv[n] = bias[w * 64 + n * 16 + lr];
#pragma unroll
        for (int m = 0; m < 4; ++m)
#pragma unroll
            for (int rr = 0; rr < 4; ++rr) {
                int row = m * 16 + lq * 4 + rr;
                int xsw = (row & 7) << 3;
#pragma unroll
                for (int n = 0; n < 4; ++n) {
                    int col = w * 64 + n * 16 + lr;
                    float v = fmaxf(acc[m][n][rr] + bv[n], 0.f);
                    Es[row * 256 + (col ^ xsw)] = f2b(v);
                }
            }
    };
    auto acc_reset = [&]() {
#pragma unroll
        for (int m = 0; m < 4; ++m)
#pragma unroll
            for (int n = 0; n < 4; ++n) acc[m][n] = (f32x4){0.f, 0.f, 0.f, 0.f};
    };

    // ---- GEMM1: K=544 (h[rs] 0..255 | h[cs] 256..511 | radial 512..543) ----
    {
        GLOAD_LDS16(hrp, As[0] + w * 512);        // prologue stage, buf 0
        stageB(We1t, 544, 0, 0);
        int cur = 0;
#pragma unroll 1
        for (int s = 0; s < 17; ++s) {
            __syncthreads();   // drains stage(s); stage(s) flew during mfma(s-1)
            int nxt = cur ^ 1;
            if (s < 15) {
                const unsigned short* sa =
                    (s + 1 < 8) ? hrp + 32 * (s + 1) : hcp + 32 * (s + 1);
                GLOAD_LDS16(sa, As[nxt] + w * 512);
                stageB(We1t, 544, nxt, 32 * (s + 1));
            } else if (s == 15) {
                // radial tail (step 16): fill As[nxt] from Rs via ds_write
                int ls = sslot ^ ((srow >> 1) & 3);
                bf16x8 v = {};
                if (ls < 2) {
#pragma unroll
                    for (int ii = 0; ii < 8; ++ii)
                        v[ii] = (short)Rs[srow][ls * 8 + ii];
                }
                *reinterpret_cast<bf16x8*>(As[nxt] + tid * 8) = v;
                stageB(We1t, 544, nxt, 512);
            }
            mfma32(cur);
            cur ^= 1;
        }
    }
    __syncthreads();               // last-step reads done; buffers free
    stageB(We2t, 256, 0, 0);       // prefetch GEMM2 step 0 (flies during epi1)
    epi_es(be1);                   // E1 -> Es

    // ---- GEMM2: E2 = relu(E1 @ We2t^T + be2), K=256 ----
    acc_reset();
    {
        int cur = 0;
#pragma unroll 1
        for (int s = 0; s < 8; ++s) {
            __syncthreads();
            if (s < 7) stageB(We2t, 256, cur ^ 1, 32 * (s + 1));
            mfma_es(cur, 32 * s);
            cur ^= 1;
        }
    }
    __syncthreads();               // all Es(E1) + Bs reads done
    stageB(Wc1t, 256, 0, 0);       // prefetch GEMM3 step 0 (flies during epi2)
    epi_es(be2);                   // E2 -> Es (overwrite)

    // ---- GEMM3: m = relu(E2 @ Wc1t^T + bc1) . Wc2, K=256 ----
    acc_reset();
    {
        int cur = 0;
#pragma unroll 1
        for (int s = 0; s < 8; ++s) {
            __syncthreads();
            if (s < 7) stageB(Wc1t, 256, cur ^ 1, 32 * (s + 1));
            mfma_es(cur, 32 * s);
            cur ^= 1;
        }
    }
    {   // epilogue 3: per-row dot with Wc2, 16-lane reduce, partials to Ms
        float bv[4], wv[4];
#pragma unroll
        for (int n = 0; n < 4; ++n) {
            int col = w * 64 + n * 16 + lr;
            bv[n] = bc1[col];
            wv[n] = Wc2[col];
        }
#pragma unroll
        for (int m = 0; m < 4; ++m)
#pragma unroll
            for (int rr = 0; rr < 4; ++rr) {
                float p = 0.f;
#pragma unroll
                for (int n = 0; n < 4; ++n)
                    p += fmaxf(acc[m][n][rr] + bv[n], 0.f) * wv[n];
                p += __shfl_xor(p, 1);
                p += __shfl_xor(p, 2);
                p += __shfl_xor(p, 4);
                p += __shfl_xor(p, 8);
                if (lr == 0) Ms[m * 16 + lq * 4 + rr][w] = p;
            }
    }
    __syncthreads();

    if (tid < 64) {   // fold per-row m into Ms[.][0]
        Ms[tid][0] = Ms[tid][0] + Ms[tid][1] + Ms[tid][2] + Ms[tid][3];
    }
    __syncthreads();

    // ---- agg: sorted rows -> boundary-flush (low-contention atomics) ----
    {
        float accv = 0.f;
        for (int i = 0; i < 64; ++i) {
            int ncur = rs[sb + i];          // uniform scalar load
            accv += b2f(Es[i * 256 + (tid ^ ((i & 7) << 3))]);
            if (i == 63 || rs[sb + i + 1] != ncur) {
                atomicAdd(&aggf[((size_t)tt * NN + ncur) * 256 + tid], accv);
                accv = 0.f;
            }
        }
    }
    // ---- csum: same boundary-flush over CDs * m ----
    if (tid < 12) {
        float a = 0.f;
        for (int i = 0; i < 64; ++i) {
            int ncur = rs[sb + i];
            a += CDs[i][tid] * Ms[i][0];
            if (i == 63 || rs[sb + i + 1] != ncur) {
                atomicAdd(&csum[((size_t)tt * NN + ncur) * 12 + tid], a);
                a = 0.f;
            }
        }
    }
}

// ---------------- node GEMM (m97 128x128, BK=32) ----------------
// EPI 0: relu -> bf16 store.  EPI 2: f32 store outf = acc + bias + resid.
template<int EPI>
__global__ __launch_bounds__(256) void gemm_kernel(
    const unsigned short* __restrict__ A, const unsigned short* __restrict__ Wt,
    const float* __restrict__ bias, unsigned short* __restrict__ Cb, int KPAD,
    const float* __restrict__ resid, float* __restrict__ outf) {
    __shared__ unsigned short As[128 * 32];
    __shared__ unsigned short Bs[128 * 32];
    int tid = threadIdx.x;
    int lane = tid & 63, w = tid >> 6;
    int wr = w >> 1, wc = w & 1;
    int blockRow = blockIdx.x * 128, colBase = blockIdx.y * 128;
    int l4 = lane >> 2;
    int seg = lane & 3;

    int ar0 = blockRow + w * 16 + l4;
    int br0 = colBase + w * 16 + l4;
    const unsigned short* pA0 = A + (size_t)ar0 * KPAD + seg * 8;
    const unsigned short* pA1 = pA0 + (size_t)64 * KPAD;
    const unsigned short* pB0 = Wt + (size_t)br0 * KPAD + seg * 8;
    const unsigned short* pB1 = pB0 + (size_t)64 * KPAD;

    unsigned short* ldsA = As + w * 512;
    unsigned short* ldsB = Bs + w * 512;

    f32x4 acc[4][4] = {};
    int lr = lane & 15, lq = lane >> 4;

    for (int k0 = 0; k0 < KPAD; k0 += 32) {
        GLOAD_LDS16(pA0 + k0, ldsA);
        GLOAD_LDS16(pA1 + k0, ldsA + 2048);
        GLOAD_LDS16(pB0 + k0, ldsB);
        GLOAD_LDS16(pB1 + k0, ldsB + 2048);
        __syncthreads();
        bf16x8 a[4], b[4];
#pragma unroll
        for (int m = 0; m < 4; ++m)
            a[m] = *reinterpret_cast<const bf16x8*>(
                As + (wr * 64 + m * 16 + lr) * 32 + lq * 8);
#pragma unroll
        for (int n = 0; n < 4; ++n)
            b[n] = *reinterpret_cast<const bf16x8*>(
                Bs + (wc * 64 + n * 16 + lr) * 32 + lq * 8);
#pragma unroll
        for (int m = 0; m < 4; ++m)
#pragma unroll
            for (int n = 0; n < 4; ++n)
                acc[m][n] = __builtin_amdgcn_mfma_f32_16x16x32_bf16(
                    a[m], b[n], acc[m][n], 0, 0, 0);
        __syncthreads();
    }

    float bv[4];
#pragma unroll
    for (int n = 0; n < 4; ++n) bv[n] = bias[colBase + wc * 64 + n * 16 + lr];

#pragma unroll
    for (int m = 0; m < 4; ++m)
#pragma unroll
        for (int r = 0; r < 4; ++r) {
            int row = blockRow + wr * 64 + m * 16 + lq * 4 + r;
#pragma unroll
            for (int n = 0; n < 4; ++n) {
                int col = colBase + wc * 64 + n * 16 + lr;
                float v = acc[m][n][r] + bv[n];
                if (EPI == 2) {
                    outf[(size_t)row * 256 + col] =
                        v + resid[(size_t)row * 256 + col];
                } else {
                    Cb[(size_t)row * 256 + col] = f2b(fmaxf(v, 0.f));
                }
            }
        }
}

// node_in[nf][768] = [others(256 f32), h(256 bf16), agg(256 f32)] as bf16
__global__ void nodein_kernel(const float* __restrict__ others,
                              const unsigned short* __restrict__ hb,
                              const float* __restrict__ aggf,
                              unsigned short* __restrict__ node_in) {
    int idx = blockIdx.x * blockDim.x + threadIdx.x;
    int stride = gridDim.x * blockDim.x;
    const int total = TT * NN * 192;
    for (; idx < total; idx += stride) {
        int nf = idx / 192, c4 = (idx - nf * 192) * 4;
        ushort4 v;
        if (c4 < 256) {
            float4 o = *reinterpret_cast<const float4*>(others + (size_t)nf * 256 + c4);
            v.x = f2b(o.x); v.y = f2b(o.y); v.z = f2b(o.z); v.w = f2b(o.w);
        } else if (c4 < 512) {
            v = *reinterpret_cast<const ushort4*>(hb + (size_t)nf * 256 + (c4 - 256));
        } else {
            float4 a = *reinterpret_cast<const float4*>(aggf + (size_t)nf * 256 + (c4 - 512));
            v.x = f2b(a.x); v.y = f2b(a.y); v.z = f2b(a.z); v.w = f2b(a.w);
        }
        *reinterpret_cast<ushort4*>(node_in + (size_t)nf * 768 + c4) = v;
    }
}

__global__ void coordout_kernel(const float* __restrict__ x, const int* __restrict__ counts,
                                const float* __restrict__ csum, float* __restrict__ outc) {
    int idx = blockIdx.x * blockDim.x + threadIdx.x;
    if (idx >= TT * NN * 12) return;
    int n = (idx / 12) & (NN - 1);
    float cnt = (float)(counts[n] > 0 ? counts[n] : 1);
    outc[idx] = x[idx] + csum[idx] / cnt;
}

// ---------------- launch ----------------

extern "C" void kernel_launch(void* const* d_in, const int* in_sizes, int n_in,
                              void* d_out, int out_size, void* d_ws, size_t ws_size,
                              hipStream_t stream) {
    const float* x = (const float*)d_in[0];
    const float* h = (const float*)d_in[1];
    const float* others = (const float*)d_in[2];
    const float* We1 = (const float*)d_in[3];
    const float* be1 = (const float*)d_in[4];
    const float* We2 = (const float*)d_in[5];
    const float* be2 = (const float*)d_in[6];
    const float* Wn1 = (const float*)d_in[7];
    const float* bn1 = (const float*)d_in[8];
    const float* Wn2 = (const float*)d_in[9];
    const float* bn2 = (const float*)d_in[10];
    const float* Wc1 = (const float*)d_in[11];
    const float* bc1 = (const float*)d_in[12];
    const float* Wc2 = (const float*)d_in[13];
    const int* ei = (const int*)d_in[14];
    const int* rows = ei;
    const int* cols = ei + EE;

    char* wsb = (char*)d_ws;
    size_t off = 0;
    auto alloc = [&](size_t bytes) {
        void* p = wsb + off;
        off = (off + bytes + 255) & ~(size_t)255;
        return p;
    };
    const int TNH = TT * NN * HH;
    unsigned short* hb = (unsigned short*)alloc((size_t)TNH * 2);
    unsigned short* We1t = (unsigned short*)alloc(256 * 544 * 2);
    unsigned short* We2t = (unsigned short*)alloc(256 * 256 * 2);
    unsigned short* Wn1t = (unsigned short*)alloc(256 * 768 * 2);
    unsigned short* Wn2t = (unsigned short*)alloc(256 * 256 * 2);
    unsigned short* Wc1t = (unsigned short*)alloc(256 * 256 * 2);
    float* aggf = (float*)alloc((size_t)TT * NN * 256 * 4);  // contiguous zero region:
    float* csum = (float*)alloc((size_t)TT * NN * 12 * 4);   // aggf | csum
    int* counts = (int*)alloc((size_t)2048 * 4);   // counts | cursor (zeroed together)
    int* cursor = (int*)alloc((size_t)2048 * 4);
    int* boff = (int*)alloc((size_t)2049 * 4);
    int* rs = (int*)alloc((size_t)EE * 4);
    int* cs = (int*)alloc((size_t)EE * 4);
    unsigned short* node_in = (unsigned short*)alloc((size_t)TT * NN * 768 * 2);
    unsigned short* Z = (unsigned short*)alloc((size_t)TT * NN * 256 * 2);
    (void)ws_size;

    // ---- setup ----
    cvt_bf16_kernel<<<2048, 256, 0, stream>>>(h, hb, TNH);
    transpose_w_kernel<<<544, 256, 0, stream>>>(We1, We1t, 528, 544);
    transpose_w_kernel<<<256, 256, 0, stream>>>(We2, We2t, 256, 256);
    transpose_w_kernel<<<768, 256, 0, stream>>>(Wn1, Wn1t, 768, 768);
    transpose_w_kernel<<<256, 256, 0, stream>>>(Wn2, Wn2t, 256, 256);
    transpose_w_kernel<<<256, 256, 0, stream>>>(Wc1, Wc1t, 256, 256);
    zero_f32_kernel<<<16, 256, 0, stream>>>((float*)counts, 4096);  // counts+cursor
    count_kernel<<<EE / 256, 256, 0, stream>>>(rows, counts);
    scan_kernel<<<1, 256, 0, stream>>>(counts, boff);
    scatter_kernel<<<EE / 256, 256, 0, stream>>>(rows, cols, boff, cursor, rs, cs);
    zero_f32_kernel<<<2048, 256, 0, stream>>>(aggf, TT * NN * 256 + TT * NN * 12);

    float* houtf = (float*)d_out;
    float* coutf = (float*)d_out + (size_t)TT * NN * HH;

    // ---- fused edge pipeline: all T, sorted edges, dbuf-pipelined K-loops ----
    edge_mega_kernel<<<TT * EE / 64, 256, 0, stream>>>(
        x, hb, We1t, be1, We2t, be2, Wc1t, bc1, Wc2, rs, cs, aggf, csum);

    // ---- node pipeline ----
    nodein_kernel<<<2048, 256, 0, stream>>>(others, hb, aggf, node_in);
    gemm_kernel<0><<<dim3(TT * NN / 128, 2), 256, 0, stream>>>(
        node_in, Wn1t, bn1, Z, 768, nullptr, nullptr);
    gemm_kernel<2><<<dim3(TT * NN / 128, 2), 256, 0, stream>>>(
        Z, Wn2t, bn2, nullptr, 256, h, houtf);

    coordout_kernel<<<(TT * NN * 12 + 255) / 256, 256, 0, stream>>>(
        x, counts, csum, coutf);
}

// Round 10
// 434.844 us; speedup vs baseline: 1.1931x; 1.0036x over previous
//
#include <hip/hip_runtime.h>
#include <hip/hip_bf16.h>
#include <stdint.h>

// Problem constants (reference: T=10, N=2048, E=32768, H=256)
#define TT 10
#define NN 2048
#define EE 32768
#define HH 256

typedef short bf16x8 __attribute__((ext_vector_type(8)));
typedef float f32x4 __attribute__((ext_vector_type(4)));

__device__ __forceinline__ float b2f(unsigned short u) {
    unsigned int x = ((unsigned int)u) << 16;
    return __builtin_bit_cast(float, x);
}
__device__ __forceinline__ unsigned short f2b(float f) {
    unsigned int x = __builtin_bit_cast(unsigned int, f);
    unsigned int r = x + 0x7FFFu + ((x >> 16) & 1u);
    return (unsigned short)(r >> 16);
}

#define GLOAD_LDS16(g, l)                                                      \
    __builtin_amdgcn_global_load_lds(                                          \
        (const __attribute__((address_space(1))) void*)(g),                    \
        (__attribute__((address_space(3))) void*)(l), 16, 0, 0)

#define WAITVM5 asm volatile("s_waitcnt vmcnt(5)" ::: "memory")
#define WAITVM4 asm volatile("s_waitcnt vmcnt(4)" ::: "memory")
#define WAITVM0 asm volatile("s_waitcnt vmcnt(0)" ::: "memory")
#define WAITLG0 asm volatile("s_waitcnt lgkmcnt(0)" ::: "memory")

// ---------------- setup kernels ----------------

__global__ void cvt_bf16_kernel(const float* __restrict__ in,
                                unsigned short* __restrict__ out, int n) {
    int i = blockIdx.x * blockDim.x + threadIdx.x;
    int stride = gridDim.x * blockDim.x;
    for (; i < n; i += stride) out[i] = f2b(in[i]);
}

// W: [K][256] row-major -> Wt: [256][KPAD] bf16, zero-padded
__global__ void transpose_w_kernel(const float* __restrict__ W,
                                   unsigned short* __restrict__ Wt, int K, int KPAD) {
    int idx = blockIdx.x * blockDim.x + threadIdx.x;
    if (idx >= 256 * KPAD) return;
    int n = idx / KPAD, k = idx - n * KPAD;
    Wt[idx] = (k < K) ? f2b(W[k * 256 + n]) : (unsigned short)0;
}

__global__ void zero_f32_kernel(float* __restrict__ p, int n) {
    int i = blockIdx.x * blockDim.x + threadIdx.x;
    int stride = gridDim.x * blockDim.x;
    for (; i < n; i += stride) p[i] = 0.0f;
}

__global__ void count_kernel(const int* __restrict__ rows, int* __restrict__ counts) {
    int e = blockIdx.x * blockDim.x + threadIdx.x;
    if (e < EE) atomicAdd(&counts[rows[e]], 1);
}

// Exclusive scan of counts[0..2047] -> boff[0..2048]. One block, 256 threads.
__global__ __launch_bounds__(256) void scan_kernel(const int* __restrict__ counts,
                                                   int* __restrict__ boff) {
    __shared__ int part[256];
    int tid = threadIdx.x;
    int base = tid * 8;
    int local[8];
    int s = 0;
#pragma unroll
    for (int i = 0; i < 8; ++i) { local[i] = s; s += counts[base + i]; }
    part[tid] = s;
    __syncthreads();
    for (int offd = 1; offd < 256; offd <<= 1) {
        int v = (tid >= offd) ? part[tid - offd] : 0;
        __syncthreads();
        part[tid] += v;
        __syncthreads();
    }
    int pbase = (tid == 0) ? 0 : part[tid - 1];
#pragma unroll
    for (int i = 0; i < 8; ++i) boff[base + i] = pbase + local[i];
    if (tid == 255) boff[2048] = pbase + s;
}

// Scatter edges into row-sorted order: rs[pos]=row, cs[pos]=col.
__global__ void scatter_kernel(const int* __restrict__ rows, const int* __restrict__ cols,
                               const int* __restrict__ boff, int* __restrict__ cursor,
                               int* __restrict__ rs, int* __restrict__ cs) {
    int e = blockIdx.x * blockDim.x + threadIdx.x;
    if (e < EE) {
        int r = rows[e];
        int pos = boff[r] + atomicAdd(&cursor[r], 1);
        rs[pos] = r;
        cs[pos] = cols[e];
    }
}

// ---------------- edge megakernel ----------------
// 64 sorted edges/block, 256 thr, 4 waves, 2 blocks/CU. BK=32 double-buffered
// K-loops with COUNTED vmcnt + raw s_barrier (m201/T4 pattern): one full stage
// (5 loads GEMM1 / 4 loads GEMM2-3) stays in flight across every barrier.
// Biases preloaded at kernel top (vmcnt retires in order — any mid-loop global
// load would force a full drain). Radial tail runs as step 0.
__global__ __launch_bounds__(256, 2) void edge_mega_kernel(
    const float* __restrict__ x, const unsigned short* __restrict__ hb,
    const unsigned short* __restrict__ We1t, const float* __restrict__ be1,
    const unsigned short* __restrict__ We2t, const float* __restrict__ be2,
    const unsigned short* __restrict__ Wc1t, const float* __restrict__ bc1,
    const float* __restrict__ Wc2,
    const int* __restrict__ rs, const int* __restrict__ cs,
    float* __restrict__ aggf, float* __restrict__ csum) {
    __shared__ unsigned short As[2][64 * 32];    // 2 x 4 KB
    __shared__ unsigned short Bs[2][256 * 32];   // 2 x 16 KB
    __shared__ unsigned short Es[64 * 256];      // 32 KB (swizzled)
    __shared__ float CDs[64][12];                // 3 KB
    __shared__ unsigned short Rs[64][16];        // 2 KB
    __shared__ float Ms[64][4];                  // 1 KB

    int tid = threadIdx.x;
    int lane = tid & 63, w = tid >> 6;
    int lr = lane & 15, lq = lane >> 4;
    int blockRow = blockIdx.x * 64;
    int tt = blockRow >> 15;                  // uniform timestep per block
    int sb = blockRow & (EE - 1);             // base sorted-index

    // ---- preload epilogue constants (forces their vmcnt drain NOW) ----
    float bv1[4], bv2[4], bv3[4], wv3[4];
#pragma unroll
    for (int n = 0; n < 4; ++n) {
        int col = w * 64 + n * 16 + lr;
        bv1[n] = be1[col];
        bv2[n] = be2[col];
        bv3[n] = bc1[col];
        wv3[n] = Wc2[col];
    }
#pragma unroll
    for (int n = 0; n < 4; ++n)
        asm volatile("" :: "v"(bv1[n]), "v"(bv2[n]), "v"(bv3[n]), "v"(wv3[n]));

    // ---- phase 0: radial + cdiff for this block's 64 sorted edges ----
    if (tid < 64) {
        int s = sb + tid;
        int r = rs[s], c = cs[s];
        const float* xr = x + ((size_t)tt * NN + r) * 12;
        const float* xc = x + ((size_t)tt * NN + c) * 12;
        float cd[12];
#pragma unroll
        for (int i = 0; i < 12; ++i) {
            cd[i] = xr[i] - xc[i];
            CDs[tid][i] = cd[i];
        }
        float g[16], ss = 0.f;
#pragma unroll
        for (int j = 0; j < 4; ++j)
#pragma unroll
            for (int k = 0; k < 4; ++k) {
                float v = cd[j * 3] * cd[k * 3] + cd[j * 3 + 1] * cd[k * 3 + 1] +
                          cd[j * 3 + 2] * cd[k * 3 + 2];
                g[j * 4 + k] = v;
                ss += v * v;
            }
        float inv = 1.f / fmaxf(sqrtf(ss), 1e-12f);
#pragma unroll
        for (int i = 0; i < 16; ++i) Rs[tid][i] = f2b(g[i] * inv);
    }

    // ---- staging geometry: thread -> (row tid>>2, 16B slot tid&3) ----
    int srow = tid >> 2, sslot = tid & 3;
    int xoff = (sslot ^ ((srow >> 1) & 3)) * 8;   // pre-swizzled source offset
    const unsigned short* hrp =
        hb + ((size_t)tt * NN + rs[sb + srow]) * 256 + xoff;
    const unsigned short* hcp =
        hb + ((size_t)tt * NN + cs[sb + srow]) * 256 + xoff - 256;
    int axoff = (lq ^ ((lr >> 1) & 3)) * 8;       // mfma A/B read swizzle

    f32x4 acc[4][4];
#pragma unroll
    for (int m = 0; m < 4; ++m)
#pragma unroll
        for (int n = 0; n < 4; ++n) acc[m][n] = (f32x4){0.f, 0.f, 0.f, 0.f};

    auto stageB = [&](const unsigned short* Wt, int KPAD, int buf, int k0) {
#pragma unroll
        for (int i = 0; i < 4; ++i)
            GLOAD_LDS16(Wt + (size_t)(i * 64 + srow) * KPAD + k0 + xoff,
                        Bs[buf] + i * 2048 + w * 512);
    };
    auto mfma32 = [&](int buf) {
        bf16x8 a[4], b[4];
#pragma unroll
        for (int m = 0; m < 4; ++m)
            a[m] = *reinterpret_cast<const bf16x8*>(
                As[buf] + (m * 16 + lr) * 32 + axoff);
#pragma unroll
        for (int n = 0; n < 4; ++n)
            b[n] = *reinterpret_cast<const bf16x8*>(
                Bs[buf] + (w * 64 + n * 16 + lr) * 32 + axoff);
        __builtin_amdgcn_s_setprio(1);
#pragma unroll
        for (int m = 0; m < 4; ++m)
#pragma unroll
            for (int n = 0; n < 4; ++n)
                acc[m][n] = __builtin_amdgcn_mfma_f32_16x16x32_bf16(
                    a[m], b[n], acc[m][n], 0, 0, 0);
        __builtin_amdgcn_s_setprio(0);
    };
    auto mfma_es = [&](int buf, int k0) {
        int ex = (k0 + lq * 8) ^ ((lr & 7) << 3);
        bf16x8 a[4], b[4];
#pragma unroll
        for (int m = 0; m < 4; ++m)
            a[m] = *reinterpret_cast<const bf16x8*>(
                Es + (m * 16 + lr) * 256 + ex);
#pragma unroll
        for (int n = 0; n < 4; ++n)
            b[n] = *reinterpret_cast<const bf16x8*>(
                Bs[buf] + (w * 64 + n * 16 + lr) * 32 + axoff);
        __builtin_amdgcn_s_setprio(1);
#pragma unroll
        for (int m = 0; m < 4; ++m)
#pragma unroll
            for (int n = 0; n < 4; ++n)
                acc[m][n] = __builtin_amdgcn_mfma_f32_16x16x32_bf16(
                    a[m], b[n], acc[m][n], 0, 0, 0);
        __builtin_amdgcn_s_setprio(0);
    };
    auto epi_es = [&](const float* bvp) {
#pragma unroll
        for (int m = 0; m < 4; ++m)
#pragma unroll
            for (int rr = 0; rr < 4; ++rr) {
                int row = m * 16 + lq * 4 + rr;
                int xsw = (row & 7) << 3;
#pragma unroll
                for (int n = 0; n < 4; ++n) {
                    int col = w * 64 + n * 16 + lr;
                    float v = fmaxf(acc[m][n][rr] + bvp[n], 0.f);
                    Es[row * 256 + (col ^ xsw)] = f2b(v);
                }
            }
    };
    auto acc_reset = [&]() {
#pragma unroll
        for (int m = 0; m < 4; ++m)
#pragma unroll
            for (int n = 0; n < 4; ++n) acc[m][n] = (f32x4){0.f, 0.f, 0.f, 0.f};
    };

    __syncthreads();   // Rs/CDs published (full drain OK: nothing staged yet)

    // ---- radial A-tile (logical K cols 512..543) -> As[0] via ds_write ----
    {
        int ls = sslot ^ ((srow >> 1) & 3);
        bf16x8 v = {};
        if (ls < 2) {
#pragma unroll
            for (int ii = 0; ii < 8; ++ii) v[ii] = (short)Rs[srow][ls * 8 + ii];
        }
        *reinterpret_cast<bf16x8*>(As[0] + tid * 8) = v;
    }
    // ---- prologue staging: step0 = radial (B cols 512), step1 = h k0=0 ----
    stageB(We1t, 544, 0, 512);           // 4 loads
    GLOAD_LDS16(hrp, As[1] + w * 512);   // +1
    stageB(We1t, 544, 1, 0);             // +4  -> 9 in flight
    WAITLG0;                              // own ds_writes (As[0]) complete

    // ---- GEMM1: 17 steps (radial + 16 h-steps), counted-vmcnt pipeline ----
#pragma unroll 1
    for (int s = 0; s < 17; ++s) {
        if (s < 16) { WAITVM5; } else { WAITVM0; }
        __builtin_amdgcn_s_barrier();
        __builtin_amdgcn_sched_barrier(0);
        mfma32(s & 1);
        __builtin_amdgcn_s_barrier();
        if (s + 2 <= 16) {
            int k0 = (s + 1) * 32;       // stage(s+2) covers h cols k0
            const unsigned short* sa = (k0 < 256) ? hrp + k0 : hcp + k0;
            GLOAD_LDS16(sa, As[s & 1] + w * 512);
            stageB(We1t, 544, s & 1, k0);
        }
    }

    // ---- transition: prefetch GEMM2 B (flies during epi1) ----
    stageB(We2t, 256, 0, 0);
    stageB(We2t, 256, 1, 32);
    epi_es(bv1);                         // E1 -> Es (ds_writes; no VMEM)
    WAITLG0;                              // own Es writes complete

    // ---- GEMM2: E2 = relu(E1 @ We2t^T + be2), 8 steps ----
    acc_reset();
#pragma unroll 1
    for (int s = 0; s < 8; ++s) {
        if (s < 7) { WAITVM4; } else { WAITVM0; }
        __builtin_amdgcn_s_barrier();
        __builtin_amdgcn_sched_barrier(0);
        mfma_es(s & 1, 32 * s);
        __builtin_amdgcn_s_barrier();
        if (s + 2 <= 7) stageB(We2t, 256, s & 1, 32 * (s + 2));
    }

    // ---- transition: prefetch GEMM3 B (flies during epi2) ----
    stageB(Wc1t, 256, 0, 0);
    stageB(Wc1t, 256, 1, 32);
    epi_es(bv2);                         // E2 -> Es (overwrite)
    WAITLG0;

    // ---- GEMM3: m = relu(E2 @ Wc1t^T + bc1) . Wc2, 8 steps ----
    acc_reset();
#pragma unroll 1
    for (int s = 0; s < 8; ++s) {
        if (s < 7) { WAITVM4; } else { WAITVM0; }
        __builtin_amdgcn_s_barrier();
        __builtin_amdgcn_sched_barrier(0);
        mfma_es(s & 1, 32 * s);
        __builtin_amdgcn_s_barrier();
        if (s + 2 <= 7) stageB(Wc1t, 256, s & 1, 32 * (s + 2));
    }

    {   // epilogue 3: per-row dot with Wc2, 16-lane reduce, partials to Ms
#pragma unroll
        for (int m = 0; m < 4; ++m)
#pragma unroll
            for (int rr = 0; rr < 4; ++rr) {
                float p = 0.f;
#pragma unroll
                for (int n = 0; n < 4; ++n)
                    p += fmaxf(acc[m][n][rr] + bv3[n], 0.f) * wv3[n];
                p += __shfl_xor(p, 1);
                p += __shfl_xor(p, 2);
                p += __shfl_xor(p, 4);
                p += __shfl_xor(p, 8);
                if (lr == 0) Ms[m * 16 + lq * 4 + rr][w] = p;
            }
    }
    __syncthreads();

    if (tid < 64) {   // fold per-row m into Ms[.][0]
        Ms[tid][0] = Ms[tid][0] + Ms[tid][1] + Ms[tid][2] + Ms[tid][3];
    }
    __syncthreads();

    // ---- agg: sorted rows -> boundary-flush (low-contention atomics) ----
    {
        float accv = 0.f;
        for (int i = 0; i < 64; ++i) {
            int ncur = rs[sb + i];          // uniform scalar load
            accv += b2f(Es[i * 256 + (tid ^ ((i & 7) << 3))]);
            if (i == 63 || rs[sb + i + 1] != ncur) {
                atomicAdd(&aggf[((size_t)tt * NN + ncur) * 256 + tid], accv);
                accv = 0.f;
            }
        }
    }
    // ---- csum: same boundary-flush over CDs * m ----
    if (tid < 12) {
        float a = 0.f;
        for (int i = 0; i < 64; ++i) {
            int ncur = rs[sb + i];
            a += CDs[i][tid] * Ms[i][0];
            if (i == 63 || rs[sb + i + 1] != ncur) {
                atomicAdd(&csum[((size_t)tt * NN + ncur) * 12 + tid], a);
                a = 0.f;
            }
        }
    }
}

// ---------------- node GEMM (m97 128x128, BK=32) ----------------
// EPI 0: relu -> bf16 store.  EPI 2: f32 store outf = acc + bias + resid.
template<int EPI>
__global__ __launch_bounds__(256) void gemm_kernel(
    const unsigned short* __restrict__ A, const unsigned short* __restrict__ Wt,
    const float* __restrict__ bias, unsigned short* __restrict__ Cb, int KPAD,
    const float* __restrict__ resid, float* __restrict__ outf) {
    __shared__ unsigned short As[128 * 32];
    __shared__ unsigned short Bs[128 * 32];
    int tid = threadIdx.x;
    int lane = tid & 63, w = tid >> 6;
    int wr = w >> 1, wc = w & 1;
    int blockRow = blockIdx.x * 128, colBase = blockIdx.y * 128;
    int l4 = lane >> 2;
    int seg = lane & 3;

    int ar0 = blockRow + w * 16 + l4;
    int br0 = colBase + w * 16 + l4;
    const unsigned short* pA0 = A + (size_t)ar0 * KPAD + seg * 8;
    const unsigned short* pA1 = pA0 + (size_t)64 * KPAD;
    const unsigned short* pB0 = Wt + (size_t)br0 * KPAD + seg * 8;
    const unsigned short* pB1 = pB0 + (size_t)64 * KPAD;

    unsigned short* ldsA = As + w * 512;
    unsigned short* ldsB = Bs + w * 512;

    f32x4 acc[4][4] = {};
    int lr = lane & 15, lq = lane >> 4;

    for (int k0 = 0; k0 < KPAD; k0 += 32) {
        GLOAD_LDS16(pA0 + k0, ldsA);
        GLOAD_LDS16(pA1 + k0, ldsA + 2048);
        GLOAD_LDS16(pB0 + k0, ldsB);
        GLOAD_LDS16(pB1 + k0, ldsB + 2048);
        __syncthreads();
        bf16x8 a[4], b[4];
#pragma unroll
        for (int m = 0; m < 4; ++m)
            a[m] = *reinterpret_cast<const bf16x8*>(
                As + (wr * 64 + m * 16 + lr) * 32 + lq * 8);
#pragma unroll
        for (int n = 0; n < 4; ++n)
            b[n] = *reinterpret_cast<const bf16x8*>(
                Bs + (wc * 64 + n * 16 + lr) * 32 + lq * 8);
#pragma unroll
        for (int m = 0; m < 4; ++m)
#pragma unroll
            for (int n = 0; n < 4; ++n)
                acc[m][n] = __builtin_amdgcn_mfma_f32_16x16x32_bf16(
                    a[m], b[n], acc[m][n], 0, 0, 0);
        __syncthreads();
    }

    float bv[4];
#pragma unroll
    for (int n = 0; n < 4; ++n) bv[n] = bias[colBase + wc * 64 + n * 16 + lr];

#pragma unroll
    for (int m = 0; m < 4; ++m)
#pragma unroll
        for (int r = 0; r < 4; ++r) {
            int row = blockRow + wr * 64 + m * 16 + lq * 4 + r;
#pragma unroll
            for (int n = 0; n < 4; ++n) {
                int col = colBase + wc * 64 + n * 16 + lr;
                float v = acc[m][n][r] + bv[n];
                if (EPI == 2) {
                    outf[(size_t)row * 256 + col] =
                        v + resid[(size_t)row * 256 + col];
                } else {
                    Cb[(size_t)row * 256 + col] = f2b(fmaxf(v, 0.f));
                }
            }
        }
}

// node_in[nf][768] = [others(256 f32), h(256 bf16), agg(256 f32)] as bf16
__global__ void nodein_kernel(const float* __restrict__ others,
                              const unsigned short* __restrict__ hb,
                              const float* __restrict__ aggf,
                              unsigned short* __restrict__ node_in) {
    int idx = blockIdx.x * blockDim.x + threadIdx.x;
    int stride = gridDim.x * blockDim.x;
    const int total = TT * NN * 192;
    for (; idx < total; idx += stride) {
        int nf = idx / 192, c4 = (idx - nf * 192) * 4;
        ushort4 v;
        if (c4 < 256) {
            float4 o = *reinterpret_cast<const float4*>(others + (size_t)nf * 256 + c4);
            v.x = f2b(o.x); v.y = f2b(o.y); v.z = f2b(o.z); v.w = f2b(o.w);
        } else if (c4 < 512) {
            v = *reinterpret_cast<const ushort4*>(hb + (size_t)nf * 256 + (c4 - 256));
        } else {
            float4 a = *reinterpret_cast<const float4*>(aggf + (size_t)nf * 256 + (c4 - 512));
            v.x = f2b(a.x); v.y = f2b(a.y); v.z = f2b(a.z); v.w = f2b(a.w);
        }
        *reinterpret_cast<ushort4*>(node_in + (size_t)nf * 768 + c4) = v;
    }
}

__global__ void coordout_kernel(const float* __restrict__ x, const int* __restrict__ counts,
                                const float* __restrict__ csum, float* __restrict__ outc) {
    int idx = blockIdx.x * blockDim.x + threadIdx.x;
    if (idx >= TT * NN * 12) return;
    int n = (idx / 12) & (NN - 1);
    float cnt = (float)(counts[n] > 0 ? counts[n] : 1);
    outc[idx] = x[idx] + csum[idx] / cnt;
}

// ---------------- launch ----------------

extern "C" void kernel_launch(void* const* d_in, const int* in_sizes, int n_in,
                              void* d_out, int out_size, void* d_ws, size_t ws_size,
                              hipStream_t stream) {
    const float* x = (const float*)d_in[0];
    const float* h = (const float*)d_in[1];
    const float* others = (const float*)d_in[2];
    const float* We1 = (const float*)d_in[3];
    const float* be1 = (const float*)d_in[4];
    const float* We2 = (const float*)d_in[5];
    const float* be2 = (const float*)d_in[6];
    const float* Wn1 = (const float*)d_in[7];
    const float* bn1 = (const float*)d_in[8];
    const float* Wn2 = (const float*)d_in[9];
    const float* bn2 = (const float*)d_in[10];
    const float* Wc1 = (const float*)d_in[11];
    const float* bc1 = (const float*)d_in[12];
    const float* Wc2 = (const float*)d_in[13];
    const int* ei = (const int*)d_in[14];
    const int* rows = ei;
    const int* cols = ei + EE;

    char* wsb = (char*)d_ws;
    size_t off = 0;
    auto alloc = [&](size_t bytes) {
        void* p = wsb + off;
        off = (off + bytes + 255) & ~(size_t)255;
        return p;
    };
    const int TNH = TT * NN * HH;
    unsigned short* hb = (unsigned short*)alloc((size_t)TNH * 2);
    unsigned short* We1t = (unsigned short*)alloc(256 * 544 * 2);
    unsigned short* We2t = (unsigned short*)alloc(256 * 256 * 2);
    unsigned short* Wn1t = (unsigned short*)alloc(256 * 768 * 2);
    unsigned short* Wn2t = (unsigned short*)alloc(256 * 256 * 2);
    unsigned short* Wc1t = (unsigned short*)alloc(256 * 256 * 2);
    float* aggf = (float*)alloc((size_t)TT * NN * 256 * 4);  // contiguous zero region:
    float* csum = (float*)alloc((size_t)TT * NN * 12 * 4);   // aggf | csum
    int* counts = (int*)alloc((size_t)2048 * 4);   // counts | cursor (zeroed together)
    int* cursor = (int*)alloc((size_t)2048 * 4);
    int* boff = (int*)alloc((size_t)2049 * 4);
    int* rs = (int*)alloc((size_t)EE * 4);
    int* cs = (int*)alloc((size_t)EE * 4);
    unsigned short* node_in = (unsigned short*)alloc((size_t)TT * NN * 768 * 2);
    unsigned short* Z = (unsigned short*)alloc((size_t)TT * NN * 256 * 2);
    (void)ws_size;

    // ---- setup ----
    cvt_bf16_kernel<<<2048, 256, 0, stream>>>(h, hb, TNH);
    transpose_w_kernel<<<544, 256, 0, stream>>>(We1, We1t, 528, 544);
    transpose_w_kernel<<<256, 256, 0, stream>>>(We2, We2t, 256, 256);
    transpose_w_kernel<<<768, 256, 0, stream>>>(Wn1, Wn1t, 768, 768);
    transpose_w_kernel<<<256, 256, 0, stream>>>(Wn2, Wn2t, 256, 256);
    transpose_w_kernel<<<256, 256, 0, stream>>>(Wc1, Wc1t, 256, 256);
    zero_f32_kernel<<<16, 256, 0, stream>>>((float*)counts, 4096);  // counts+cursor
    count_kernel<<<EE / 256, 256, 0, stream>>>(rows, counts);
    scan_kernel<<<1, 256, 0, stream>>>(counts, boff);
    scatter_kernel<<<EE / 256, 256, 0, stream>>>(rows, cols, boff, cursor, rs, cs);
    zero_f32_kernel<<<2048, 256, 0, stream>>>(aggf, TT * NN * 256 + TT * NN * 12);

    float* houtf = (float*)d_out;
    float* coutf = (float*)d_out + (size_t)TT * NN * HH;

    // ---- fused edge pipeline: all T, sorted edges, counted-vmcnt pipeline ----
    edge_mega_kernel<<<TT * EE / 64, 256, 0, stream>>>(
        x, hb, We1t, be1, We2t, be2, Wc1t, bc1, Wc2, rs, cs, aggf, csum);

    // ---- node pipeline ----
    nodein_kernel<<<2048, 256, 0, stream>>>(others, hb, aggf, node_in);
    gemm_kernel<0><<<dim3(TT * NN / 128, 2), 256, 0, stream>>>(
        node_in, Wn1t, bn1, Z, 768, nullptr, nullptr);
    gemm_kernel<2><<<dim3(TT * NN / 128, 2), 256, 0, stream>>>(
        Z, Wn2t, bn2, nullptr, 256, h, houtf);

    coordout_kernel<<<(TT * NN * 12 + 255) / 256, 256, 0, stream>>>(
        x, counts, csum, coutf);
}